// Round 1
// baseline (564.276 us; speedup 1.0000x reference)
//
#include <hip/hip_runtime.h>
#include <math.h>

// Problem: B=262144, IN_DIM=2, OUT_DIM=256
// out[0 .. B*256)   = cos(x @ h^T + delta)   (row-major [B,256], f32)
// out[B*256]        = sum_o atan2(mean_b sin, mean_b cos) / pi
//
// Memory-bound: 256 MB of stores dominates. One wave per row: 64 lanes x
// float4 = 256 columns, contiguous 1 KB store per row. Column sums kept in
// registers, LDS-reduced across the 4 row-slots per block, written as
// per-block partials to d_ws (fully overwritten each launch -> no memset
// needed despite 0xAA poisoning). Second tiny kernel folds partials into eta.

#define B_DIM 262144
#define O_DIM 256

__global__ __launch_bounds__(256) void fdc_main(
    const float* __restrict__ x, const float* __restrict__ h,
    const float* __restrict__ delta, float* __restrict__ out,
    float* __restrict__ partial /* [gridDim.x][512] */) {
  const int tid  = threadIdx.x;
  const int lane = tid & 63;   // which group of 4 columns
  const int rl   = tid >> 6;   // row slot 0..3 within block
  const int col4 = lane * 4;

  // Preload weights for this thread's 4 columns.
  // h is [256][2] row-major: cols col4..col4+3 occupy 8 consecutive floats.
  const float4* h4 = (const float4*)h;
  const float4 ha = h4[lane * 2];      // (h[c0][0], h[c0][1], h[c1][0], h[c1][1])
  const float4 hb = h4[lane * 2 + 1];  // (h[c2][0], h[c2][1], h[c3][0], h[c3][1])
  const float4 dl = ((const float4*)delta)[lane];

  const float2* x2 = (const float2*)x;
  float4* out4 = (float4*)out;

  float sc0 = 0.f, sc1 = 0.f, sc2 = 0.f, sc3 = 0.f;
  float ss0 = 0.f, ss1 = 0.f, ss2 = 0.f, ss3 = 0.f;

  const int stride = gridDim.x * 4;
  for (int row = blockIdx.x * 4 + rl; row < B_DIM; row += stride) {
    const float2 xv = x2[row];  // broadcast across the wave (same addr)
    float s, c;
    float4 o;
    const float t0 = fmaf(xv.x, ha.x, fmaf(xv.y, ha.y, dl.x));
    const float t1 = fmaf(xv.x, ha.z, fmaf(xv.y, ha.w, dl.y));
    const float t2 = fmaf(xv.x, hb.x, fmaf(xv.y, hb.y, dl.z));
    const float t3 = fmaf(xv.x, hb.z, fmaf(xv.y, hb.w, dl.w));
    __sincosf(t0, &s, &c); o.x = c; sc0 += c; ss0 += s;
    __sincosf(t1, &s, &c); o.y = c; sc1 += c; ss1 += s;
    __sincosf(t2, &s, &c); o.z = c; sc2 += c; ss2 += s;
    __sincosf(t3, &s, &c); o.w = c; sc3 += c; ss3 += s;
    out4[(size_t)row * 64 + lane] = o;  // 64 lanes -> 1 KB contiguous
  }

  // Reduce the 4 row-slots' column sums -> per-block partial [512].
  __shared__ float lds[4][512];
  lds[rl][col4 + 0] = sc0; lds[rl][col4 + 1] = sc1;
  lds[rl][col4 + 2] = sc2; lds[rl][col4 + 3] = sc3;
  lds[rl][256 + col4 + 0] = ss0; lds[rl][256 + col4 + 1] = ss1;
  lds[rl][256 + col4 + 2] = ss2; lds[rl][256 + col4 + 3] = ss3;
  __syncthreads();
  const float a = lds[0][tid] + lds[1][tid] + lds[2][tid] + lds[3][tid];
  const float b = lds[0][tid + 256] + lds[1][tid + 256] +
                  lds[2][tid + 256] + lds[3][tid + 256];
  float* p = partial + (size_t)blockIdx.x * 512;
  p[tid] = a;         // cos sums, cols 0..255
  p[256 + tid] = b;   // sin sums
}

__global__ __launch_bounds__(256) void fdc_eta(
    const float* __restrict__ partial, int nb, float* __restrict__ out) {
  const int o = threadIdx.x;
  double cs = 0.0, sn = 0.0;
  for (int b = 0; b < nb; ++b) {
    cs += partial[(size_t)b * 512 + o];        // coalesced across threads
    sn += partial[(size_t)b * 512 + 256 + o];
  }
  // atan2(mean_i, mean_r) == atan2(sum_i, sum_r): scale cancels.
  float ang = atan2f((float)sn, (float)cs);
  __shared__ float red[256];
  red[o] = ang;
  __syncthreads();
  for (int st = 128; st > 0; st >>= 1) {
    if (o < st) red[o] += red[o + st];
    __syncthreads();
  }
  if (o == 0) out[(size_t)B_DIM * O_DIM] = red[0] * (float)(1.0 / M_PI);
}

extern "C" void kernel_launch(void* const* d_in, const int* in_sizes, int n_in,
                              void* d_out, int out_size, void* d_ws, size_t ws_size,
                              hipStream_t stream) {
  const float* x     = (const float*)d_in[0];
  const float* h     = (const float*)d_in[1];
  const float* delta = (const float*)d_in[2];
  float* out = (float*)d_out;
  float* partial = (float*)d_ws;

  // Blocks: 1024 (4/CU) unless workspace is smaller than 1024*512*4 = 2 MB.
  int nb = 1024;
  const size_t need_per_block = 512 * sizeof(float);
  if (ws_size < (size_t)nb * need_per_block) {
    nb = (int)(ws_size / need_per_block);
    if (nb > 512) nb = 512; else if (nb > 256) nb = 256;
    else if (nb > 128) nb = 128; else if (nb > 64) nb = 64;
    if (nb < 1) nb = 1;
  }

  fdc_main<<<nb, 256, 0, stream>>>(x, h, delta, out, partial);
  fdc_eta<<<1, 256, 0, stream>>>(partial, nb, out);
}

// Round 3
// 294.216 us; speedup vs baseline: 1.9179x; 1.9179x over previous
//
#include <hip/hip_runtime.h>
#include <math.h>

// Problem: B=262144, IN_DIM=2, OUT_DIM=256
// out[0 .. B*256)   = cos(x @ h^T + delta)   (row-major [B,256], f32)
// out[B*256]        = sum_o atan2(mean_b sin, mean_b cos) / pi
//
// R1: fdc_eta was 286 us (1 block, serial loop over 1024 partials -> latency
// bound on one CU). Split into 256-block column reduce + 1-block finalize.
// Main: grid 1024 -> 2048 (32 waves/CU), nontemporal stores for the 256 MB
// out stream. R2 fix: nontemporal builtin needs a clang native vector type,
// not HIP's float4 struct.

#define B_DIM 262144
#define O_DIM 256

typedef float vf4 __attribute__((ext_vector_type(4)));

__global__ __launch_bounds__(256) void fdc_main(
    const float* __restrict__ x, const float* __restrict__ h,
    const float* __restrict__ delta, float* __restrict__ out,
    float* __restrict__ partial /* [gridDim.x][512] */) {
  const int tid  = threadIdx.x;
  const int lane = tid & 63;   // which group of 4 columns
  const int rl   = tid >> 6;   // row slot 0..3 within block
  const int col4 = lane * 4;

  // h is [256][2] row-major: cols col4..col4+3 occupy 8 consecutive floats.
  const float4* h4 = (const float4*)h;
  const float4 ha = h4[lane * 2];
  const float4 hb = h4[lane * 2 + 1];
  const float4 dl = ((const float4*)delta)[lane];

  const float2* x2 = (const float2*)x;
  vf4* out4 = (vf4*)out;

  float sc0 = 0.f, sc1 = 0.f, sc2 = 0.f, sc3 = 0.f;
  float ss0 = 0.f, ss1 = 0.f, ss2 = 0.f, ss3 = 0.f;

  const int stride = gridDim.x * 4;
  for (int row = blockIdx.x * 4 + rl; row < B_DIM; row += stride) {
    const float2 xv = x2[row];  // wave-uniform address -> one 8B transaction
    float s, c;
    vf4 o;
    const float t0 = fmaf(xv.x, ha.x, fmaf(xv.y, ha.y, dl.x));
    const float t1 = fmaf(xv.x, ha.z, fmaf(xv.y, ha.w, dl.y));
    const float t2 = fmaf(xv.x, hb.x, fmaf(xv.y, hb.y, dl.z));
    const float t3 = fmaf(xv.x, hb.z, fmaf(xv.y, hb.w, dl.w));
    __sincosf(t0, &s, &c); o.x = c; sc0 += c; ss0 += s;
    __sincosf(t1, &s, &c); o.y = c; sc1 += c; ss1 += s;
    __sincosf(t2, &s, &c); o.z = c; sc2 += c; ss2 += s;
    __sincosf(t3, &s, &c); o.w = c; sc3 += c; ss3 += s;
    __builtin_nontemporal_store(o, &out4[(size_t)row * 64 + lane]);
  }

  // Reduce the 4 row-slots' column sums -> per-block partial [512].
  __shared__ float lds[4][512];
  lds[rl][col4 + 0] = sc0; lds[rl][col4 + 1] = sc1;
  lds[rl][col4 + 2] = sc2; lds[rl][col4 + 3] = sc3;
  lds[rl][256 + col4 + 0] = ss0; lds[rl][256 + col4 + 1] = ss1;
  lds[rl][256 + col4 + 2] = ss2; lds[rl][256 + col4 + 3] = ss3;
  __syncthreads();
  const float a = lds[0][tid] + lds[1][tid] + lds[2][tid] + lds[3][tid];
  const float b = lds[0][tid + 256] + lds[1][tid + 256] +
                  lds[2][tid + 256] + lds[3][tid + 256];
  float* p = partial + (size_t)blockIdx.x * 512;
  p[tid] = a;         // cos sums, cols 0..255
  p[256 + tid] = b;   // sin sums
}

// Stage 2: one block per output column. Sum cos/sin over nb partials in
// parallel, compute atan2, write per-column angle.
__global__ __launch_bounds__(256) void fdc_colred(
    const float* __restrict__ partial, int nb, float* __restrict__ angle) {
  const int o = blockIdx.x;   // column 0..255
  const int t = threadIdx.x;
  float cs = 0.f, sn = 0.f;
  for (int b = t; b < nb; b += 256) {
    cs += partial[(size_t)b * 512 + o];
    sn += partial[(size_t)b * 512 + 256 + o];
  }
  __shared__ float rc[256], rs[256];
  rc[t] = cs; rs[t] = sn;
  __syncthreads();
  for (int st = 128; st > 0; st >>= 1) {
    if (t < st) { rc[t] += rc[t + st]; rs[t] += rs[t + st]; }
    __syncthreads();
  }
  if (t == 0) angle[o] = atan2f(rs[0], rc[0]);  // scale by 1/B cancels
}

// Stage 3: reduce 256 angles -> eta.
__global__ __launch_bounds__(256) void fdc_final(
    const float* __restrict__ angle, float* __restrict__ out) {
  const int t = threadIdx.x;
  __shared__ float red[256];
  red[t] = angle[t];
  __syncthreads();
  for (int st = 128; st > 0; st >>= 1) {
    if (t < st) red[t] += red[t + st];
    __syncthreads();
  }
  if (t == 0) out[(size_t)B_DIM * O_DIM] = red[0] * (float)(1.0 / M_PI);
}

extern "C" void kernel_launch(void* const* d_in, const int* in_sizes, int n_in,
                              void* d_out, int out_size, void* d_ws, size_t ws_size,
                              hipStream_t stream) {
  const float* x     = (const float*)d_in[0];
  const float* h     = (const float*)d_in[1];
  const float* delta = (const float*)d_in[2];
  float* out = (float*)d_out;
  float* partial = (float*)d_ws;

  // Blocks: 2048 (8/CU, 32 waves/CU) if workspace allows; partial needs
  // nb*512*4 bytes plus 256 floats for angles.
  int nb = 2048;
  const size_t per_block = 512 * sizeof(float);
  while (nb > 1 && ws_size < (size_t)nb * per_block + 256 * sizeof(float))
    nb >>= 1;
  float* angle = partial + (size_t)nb * 512;

  fdc_main<<<nb, 256, 0, stream>>>(x, h, delta, out, partial);
  fdc_colred<<<256, 256, 0, stream>>>(partial, nb, angle);
  fdc_final<<<1, 256, 0, stream>>>(angle, out);
}

// Round 4
// 287.547 us; speedup vs baseline: 1.9624x; 1.0232x over previous
//
#include <hip/hip_runtime.h>
#include <math.h>

// Problem: B=262144, IN_DIM=2, OUT_DIM=256
// out[0 .. B*256)   = cos(x @ h^T + delta)   (row-major [B,256], f32)
// out[B*256]        = sum_o atan2(mean_b sin, mean_b cos) / pi
//
// R3 forensics: top-5 dispatches are all harness poison fills (~170us, 1 GiB
// @ 6.3 TB/s). fdc_main < 170us. Decomposition: ~213us fixed poison fills +
// main ~60us + colred ~20us + final ~2us.
// R4: colred was uncoalesced (2KB stride between threads). New reduction:
// stage2 = 64 blocks, coalesced 16-row sums; stage3 = 1 block fold + atan2.
// Main: 2 rows/thread/iter, 1024 blocks, NT stores (don't evict partial
// from L2).

#define B_DIM 262144
#define O_DIM 256
#define NB1 1024   // main blocks -> partial[NB1][512] = 2 MB
#define NB2 64     // stage2 blocks, each sums NB1/NB2 = 16 rows

typedef float vf4 __attribute__((ext_vector_type(4)));

__global__ __launch_bounds__(256) void fdc_main(
    const float* __restrict__ x, const float* __restrict__ h,
    const float* __restrict__ delta, float* __restrict__ out,
    float* __restrict__ partial /* [NB1][512] */) {
  const int tid  = threadIdx.x;
  const int lane = tid & 63;   // which group of 4 columns
  const int rl   = tid >> 6;   // row slot 0..3 within block
  const int col4 = lane * 4;

  // h is [256][2] row-major: cols col4..col4+3 occupy 8 consecutive floats.
  const float4* h4 = (const float4*)h;
  const float4 ha = h4[lane * 2];
  const float4 hb = h4[lane * 2 + 1];
  const float4 dl = ((const float4*)delta)[lane];

  const float2* x2 = (const float2*)x;
  vf4* out4 = (vf4*)out;

  float sc0 = 0.f, sc1 = 0.f, sc2 = 0.f, sc3 = 0.f;
  float ss0 = 0.f, ss1 = 0.f, ss2 = 0.f, ss3 = 0.f;

  // Block covers 8 consecutive rows per iteration: wave rl handles rows
  // base+rl*2 and base+rl*2+1 (2 KB contiguous store per wave per iter).
  const int stride = NB1 * 8;
  for (int base = blockIdx.x * 8 + rl * 2; base < B_DIM; base += stride) {
#pragma unroll
    for (int k = 0; k < 2; ++k) {
      const int row = base + k;
      const float2 xv = x2[row];  // wave-uniform address
      float s, c;
      vf4 o;
      const float t0 = fmaf(xv.x, ha.x, fmaf(xv.y, ha.y, dl.x));
      const float t1 = fmaf(xv.x, ha.z, fmaf(xv.y, ha.w, dl.y));
      const float t2 = fmaf(xv.x, hb.x, fmaf(xv.y, hb.y, dl.z));
      const float t3 = fmaf(xv.x, hb.z, fmaf(xv.y, hb.w, dl.w));
      __sincosf(t0, &s, &c); o.x = c; sc0 += c; ss0 += s;
      __sincosf(t1, &s, &c); o.y = c; sc1 += c; ss1 += s;
      __sincosf(t2, &s, &c); o.z = c; sc2 += c; ss2 += s;
      __sincosf(t3, &s, &c); o.w = c; sc3 += c; ss3 += s;
      __builtin_nontemporal_store(o, &out4[(size_t)row * 64 + lane]);
    }
  }

  // Reduce the 4 row-slots' column sums -> per-block partial [512].
  __shared__ float lds[4][512];
  lds[rl][col4 + 0] = sc0; lds[rl][col4 + 1] = sc1;
  lds[rl][col4 + 2] = sc2; lds[rl][col4 + 3] = sc3;
  lds[rl][256 + col4 + 0] = ss0; lds[rl][256 + col4 + 1] = ss1;
  lds[rl][256 + col4 + 2] = ss2; lds[rl][256 + col4 + 3] = ss3;
  __syncthreads();
  const float a = lds[0][tid] + lds[1][tid] + lds[2][tid] + lds[3][tid];
  const float b = lds[0][tid + 256] + lds[1][tid + 256] +
                  lds[2][tid + 256] + lds[3][tid + 256];
  float* p = partial + (size_t)blockIdx.x * 512;
  p[tid] = a;         // cos sums, cols 0..255
  p[256 + tid] = b;   // sin sums
}

// Stage 2: NB2 blocks; each coalescedly sums 16 partial rows -> partial2 row.
__global__ __launch_bounds__(256) void fdc_red1(
    const float* __restrict__ partial, float* __restrict__ partial2) {
  const int t = threadIdx.x;
  const float* base = partial + (size_t)blockIdx.x * (NB1 / NB2) * 512;
  float cs = 0.f, sn = 0.f;
#pragma unroll
  for (int r = 0; r < NB1 / NB2; ++r) {
    cs += base[r * 512 + t];         // threads 0..255 -> 1 KB contiguous
    sn += base[r * 512 + 256 + t];
  }
  partial2[(size_t)blockIdx.x * 512 + t] = cs;
  partial2[(size_t)blockIdx.x * 512 + 256 + t] = sn;
}

// Stage 3: fold NB2 rows, atan2 per column, LDS-reduce 256 angles -> eta.
__global__ __launch_bounds__(256) void fdc_red2(
    const float* __restrict__ partial2, float* __restrict__ out) {
  const int t = threadIdx.x;
  float cs = 0.f, sn = 0.f;
#pragma unroll 4
  for (int r = 0; r < NB2; ++r) {
    cs += partial2[(size_t)r * 512 + t];
    sn += partial2[(size_t)r * 512 + 256 + t];
  }
  float ang = atan2f(sn, cs);  // 1/B scale cancels in atan2
  __shared__ float red[256];
  red[t] = ang;
  __syncthreads();
  for (int st = 128; st > 0; st >>= 1) {
    if (t < st) red[t] += red[t + st];
    __syncthreads();
  }
  if (t == 0) out[(size_t)B_DIM * O_DIM] = red[0] * (float)(1.0 / M_PI);
}

extern "C" void kernel_launch(void* const* d_in, const int* in_sizes, int n_in,
                              void* d_out, int out_size, void* d_ws, size_t ws_size,
                              hipStream_t stream) {
  const float* x     = (const float*)d_in[0];
  const float* h     = (const float*)d_in[1];
  const float* delta = (const float*)d_in[2];
  float* out = (float*)d_out;
  float* partial  = (float*)d_ws;                       // NB1*512 floats = 2 MB
  float* partial2 = partial + (size_t)NB1 * 512;        // NB2*512 floats = 128 KB
  (void)ws_size;  // harness ws is ~1 GiB (poison fill evidence); we use 2.13 MB

  fdc_main<<<NB1, 256, 0, stream>>>(x, h, delta, out, partial);
  fdc_red1<<<NB2, 256, 0, stream>>>(partial, partial2);
  fdc_red2<<<1, 256, 0, stream>>>(partial2, out);
}

// Round 5
// 277.302 us; speedup vs baseline: 2.0349x; 1.0369x over previous
//
#include <hip/hip_runtime.h>
#include <math.h>

// Problem: B=262144, IN_DIM=2, OUT_DIM=256
// out[0 .. B*256)   = cos(x @ h^T + delta)   (row-major [B,256], f32)
// out[B*256]        = sum_o atan2(mean_b sin, mean_b cos) / pi
//
// Decomposition (R3/R4 forensics): dur_us includes ~212us of harness poison
// fills (1 GiB ws @6.4 TB/s + 268 MB out). Our budget: main + red1 + red2.
// R5: main was ~60-70us vs 41us store floor. Hypothesis: per-iter serial
// uniform x-load latency. Fix: stage the block's whole x segment (1 KB) into
// LDS with one coalesced load; store loop = LDS broadcast + compute + NT
// store only. 2048 blocks (32 waves/CU, best measured).

#define B_DIM 262144
#define O_DIM 256
#define NB1 2048   // main blocks -> partial[NB1][512] = 4 MB
#define NB2 64     // stage2 blocks, each sums NB1/NB2 = 32 rows
#define ROWS_PER_BLOCK (B_DIM / NB1)   // 128
#define ROWS_PER_WAVE (ROWS_PER_BLOCK / 4)  // 32

typedef float vf4 __attribute__((ext_vector_type(4)));

__global__ __launch_bounds__(256) void fdc_main(
    const float* __restrict__ x, const float* __restrict__ h,
    const float* __restrict__ delta, float* __restrict__ out,
    float* __restrict__ partial /* [NB1][512] */) {
  const int tid  = threadIdx.x;
  const int lane = tid & 63;   // group of 4 columns
  const int wv   = tid >> 6;   // wave 0..3
  const int col4 = lane * 4;

  // h is [256][2] row-major: cols col4..col4+3 occupy 8 consecutive floats.
  const float4* h4 = (const float4*)h;
  const float4 ha = h4[lane * 2];
  const float4 hb = h4[lane * 2 + 1];
  const float4 dl = ((const float4*)delta)[lane];

  // Stage this block's x rows (128 rows x float2 = 256 floats) via one
  // coalesced load -> no global-load latency inside the store loop.
  __shared__ float2 xs[ROWS_PER_BLOCK];
  ((float*)xs)[tid] = x[(size_t)blockIdx.x * (ROWS_PER_BLOCK * 2) + tid];
  __syncthreads();

  vf4* out4 = (vf4*)out;
  float sc0 = 0.f, sc1 = 0.f, sc2 = 0.f, sc3 = 0.f;
  float ss0 = 0.f, ss1 = 0.f, ss2 = 0.f, ss3 = 0.f;

  const int rbase = blockIdx.x * ROWS_PER_BLOCK + wv * ROWS_PER_WAVE;
  const int lbase = wv * ROWS_PER_WAVE;
#pragma unroll 4
  for (int i = 0; i < ROWS_PER_WAVE; ++i) {
    const float2 xv = xs[lbase + i];   // LDS broadcast, conflict-free
    const int row = rbase + i;
    float s, c;
    vf4 o;
    const float t0 = fmaf(xv.x, ha.x, fmaf(xv.y, ha.y, dl.x));
    const float t1 = fmaf(xv.x, ha.z, fmaf(xv.y, ha.w, dl.y));
    const float t2 = fmaf(xv.x, hb.x, fmaf(xv.y, hb.y, dl.z));
    const float t3 = fmaf(xv.x, hb.z, fmaf(xv.y, hb.w, dl.w));
    __sincosf(t0, &s, &c); o.x = c; sc0 += c; ss0 += s;
    __sincosf(t1, &s, &c); o.y = c; sc1 += c; ss1 += s;
    __sincosf(t2, &s, &c); o.z = c; sc2 += c; ss2 += s;
    __sincosf(t3, &s, &c); o.w = c; sc3 += c; ss3 += s;
    __builtin_nontemporal_store(o, &out4[(size_t)row * 64 + lane]);
  }

  // Reduce the 4 waves' column sums -> per-block partial [512].
  __shared__ float lds[4][512];
  lds[wv][col4 + 0] = sc0; lds[wv][col4 + 1] = sc1;
  lds[wv][col4 + 2] = sc2; lds[wv][col4 + 3] = sc3;
  lds[wv][256 + col4 + 0] = ss0; lds[wv][256 + col4 + 1] = ss1;
  lds[wv][256 + col4 + 2] = ss2; lds[wv][256 + col4 + 3] = ss3;
  __syncthreads();
  const float a = lds[0][tid] + lds[1][tid] + lds[2][tid] + lds[3][tid];
  const float b = lds[0][tid + 256] + lds[1][tid + 256] +
                  lds[2][tid + 256] + lds[3][tid + 256];
  float* p = partial + (size_t)blockIdx.x * 512;
  p[tid] = a;         // cos sums, cols 0..255
  p[256 + tid] = b;   // sin sums
}

// Stage 2: NB2 blocks; each coalescedly sums NB1/NB2 partial rows.
__global__ __launch_bounds__(256) void fdc_red1(
    const float* __restrict__ partial, float* __restrict__ partial2) {
  const int t = threadIdx.x;
  const float* base = partial + (size_t)blockIdx.x * (NB1 / NB2) * 512;
  float cs = 0.f, sn = 0.f;
#pragma unroll 8
  for (int r = 0; r < NB1 / NB2; ++r) {
    cs += base[r * 512 + t];         // threads 0..255 -> 1 KB contiguous
    sn += base[r * 512 + 256 + t];
  }
  partial2[(size_t)blockIdx.x * 512 + t] = cs;
  partial2[(size_t)blockIdx.x * 512 + 256 + t] = sn;
}

// Stage 3: fold NB2 rows, atan2 per column, LDS-reduce 256 angles -> eta.
__global__ __launch_bounds__(256) void fdc_red2(
    const float* __restrict__ partial2, float* __restrict__ out) {
  const int t = threadIdx.x;
  float cs = 0.f, sn = 0.f;
#pragma unroll 4
  for (int r = 0; r < NB2; ++r) {
    cs += partial2[(size_t)r * 512 + t];
    sn += partial2[(size_t)r * 512 + 256 + t];
  }
  float ang = atan2f(sn, cs);  // 1/B scale cancels in atan2
  __shared__ float red[256];
  red[t] = ang;
  __syncthreads();
  for (int st = 128; st > 0; st >>= 1) {
    if (t < st) red[t] += red[t + st];
    __syncthreads();
  }
  if (t == 0) out[(size_t)B_DIM * O_DIM] = red[0] * (float)(1.0 / M_PI);
}

extern "C" void kernel_launch(void* const* d_in, const int* in_sizes, int n_in,
                              void* d_out, int out_size, void* d_ws, size_t ws_size,
                              hipStream_t stream) {
  const float* x     = (const float*)d_in[0];
  const float* h     = (const float*)d_in[1];
  const float* delta = (const float*)d_in[2];
  float* out = (float*)d_out;
  float* partial  = (float*)d_ws;                  // NB1*512 floats = 4 MB
  float* partial2 = partial + (size_t)NB1 * 512;   // NB2*512 floats = 128 KB
  (void)ws_size;

  fdc_main<<<NB1, 256, 0, stream>>>(x, h, delta, out, partial);
  fdc_red1<<<NB2, 256, 0, stream>>>(partial, partial2);
  fdc_red2<<<1, 256, 0, stream>>>(partial2, out);
}